// Round 11
// baseline (82.222 us; speedup 1.0000x reference)
//
#include <hip/hip_runtime.h>
#include <math.h>

#define NTOK 2048
#define DMODEL 512
#define NH 8
#define HD 64
#define NF 128
#define QKV_LD 1536
#define CHUNK 64
#define NCHUNK 32
#define EPS_C 1e-8f

typedef __bf16 bf16x8 __attribute__((ext_vector_type(8)));
typedef float f32x4 __attribute__((ext_vector_type(4)));

__device__ inline unsigned short f2bf(float f) {
  union { float f; unsigned u; } v; v.f = f;
  unsigned r = v.u + 0x7FFF + ((v.u >> 16) & 1);   // RNE
  return (unsigned short)(r >> 16);
}
__device__ inline unsigned short bfbits(float f) {
  union { __bf16 h; unsigned short s; } u; u.h = (__bf16)f; return u.s;  // RNE (v_cvt)
}
__device__ inline bf16x8 cvt8(const float* p) {
  const float4 a = *(const float4*)p;
  const float4 b = *(const float4*)(p + 4);
  bf16x8 r;
  r[0] = (__bf16)a.x; r[1] = (__bf16)a.y; r[2] = (__bf16)a.z; r[3] = (__bf16)a.w;
  r[4] = (__bf16)b.x; r[5] = (__bf16)b.y; r[6] = (__bf16)b.z; r[7] = (__bf16)b.w;
  return r;
}

// Packed fragment layout PK(M,K) (A: [m][k]; B: [n][k]):
//   unit(m,k) = ((m>>4)*(K>>5) + (k>>5))*64 + (m&15) + ((k>>3)&3)*16, elem = k&7

// ============ fused qkv GEMM (fp32 in, in-kernel cvt) + proj + elu+1 ============
// grid (24, 32): bx = 64-col tile (0-7 Q, 8-15 K, 16-23 V), by = chunk.
// A-fragments: direct fp32 x loads + cvt. B: W_qkv staged per-128-K-slice in LDS.
__global__ __launch_bounds__(256) void qkv_proj(
    const float* __restrict__ x, const float* __restrict__ W_qkv,
    const float* __restrict__ projf,
    unsigned short* __restrict__ q_pk, unsigned short* __restrict__ k_pk,
    unsigned short* __restrict__ kT_pk, unsigned short* __restrict__ vT_pk)
{
  __shared__ unsigned short Bs[8192];   // PK(64,128) W-slice / PK(128,64) proj, 16 KB
  __shared__ unsigned short QK[4096];   // PK(64,64), 8 KB
  const int t = threadIdx.x;
  const int lane = t & 63, w = t >> 6;
  const int wr = w >> 1, wc = w & 1;
  const int c = blockIdx.y, bx = blockIdx.x;
  const int n0 = bx * 64;
  const int r16 = lane & 15, kg = lane >> 4;
  const int m0 = c * 64 + wr * 32;
  f32x4 acc00 = {0.f, 0.f, 0.f, 0.f}, acc01 = acc00, acc10 = acc00, acc11 = acc00;

  for (int st = 0; st < 4; ++st) {
    // ---- stage W_qkv[st*128..+128)[n0..+64) -> Bs in PK(64,128) (n, kl) ----
    const float* wsrc = W_qkv + (size_t)(st * 128) * QKV_LD + n0;
#pragma unroll
    for (int i = 0; i < 8; ++i) {
      const int idx = t * 8 + i;              // 0..2047
      const int kl = idx >> 4, n4 = (idx & 15) * 4;
      const float4 v4 = *(const float4*)&wsrc[(size_t)kl * QKV_LD + n4];
      const float fe[4] = {v4.x, v4.y, v4.z, v4.w};
#pragma unroll
      for (int e = 0; e < 4; ++e) {
        const int n = n4 + e;
        const int u = ((n >> 4) * 4 + (kl >> 5)) * 64 + (n & 15) + ((kl >> 3) & 3) * 16;
        Bs[u * 8 + (kl & 7)] = bfbits(fe[e]);
      }
    }
    __syncthreads();
    // ---- 4 MFMA k-steps: A direct from x (fp32+cvt), B from Bs ----
#pragma unroll
    for (int sl = 0; sl < 4; ++sl) {
      const int k = st * 128 + sl * 32 + kg * 8;
      const bf16x8 af0 = cvt8(&x[(size_t)(m0 + r16) * 512 + k]);
      const bf16x8 af1 = cvt8(&x[(size_t)(m0 + 16 + r16) * 512 + k]);
      const bf16x8 bv0 = *(const bf16x8*)&Bs[(((wc * 2 + 0) * 4 + sl) * 64 + lane) * 8];
      const bf16x8 bv1 = *(const bf16x8*)&Bs[(((wc * 2 + 1) * 4 + sl) * 64 + lane) * 8];
      acc00 = __builtin_amdgcn_mfma_f32_16x16x32_bf16(af0, bv0, acc00, 0, 0, 0);
      acc01 = __builtin_amdgcn_mfma_f32_16x16x32_bf16(af0, bv1, acc01, 0, 0, 0);
      acc10 = __builtin_amdgcn_mfma_f32_16x16x32_bf16(af1, bv0, acc10, 0, 0, 0);
      acc11 = __builtin_amdgcn_mfma_f32_16x16x32_bf16(af1, bv1, acc11, 0, 0, 0);
    }
    __syncthreads();
  }

  if (bx < 16) {
    const int src = bx >> 3, h = bx & 7;
    // ---- qkv tile -> QK LDS PK(64,64) ----
#pragma unroll
    for (int mb = 0; mb < 2; ++mb) {
#pragma unroll
      for (int nb = 0; nb < 2; ++nb) {
        const f32x4 a = mb == 0 ? (nb == 0 ? acc00 : acc01) : (nb == 0 ? acc10 : acc11);
        const size_t u = ((size_t)(wr * 2 + mb) * 2 + wc) * 64 +
                         (nb * 2 + (r16 >> 3)) * 16 + kg * 4;
        const int elem = r16 & 7;
#pragma unroll
        for (int r = 0; r < 4; ++r)
          QK[(u + r) * 8 + elem] = f2bf(a[r]);
      }
    }
    // ---- stage proj[h] (64x128 fp32) -> Bs in PK(128,64) (n, k) ----
    const float* psrc = projf + (size_t)h * HD * NF;
#pragma unroll
    for (int i = 0; i < 8; ++i) {
      const int idx = t * 8 + i;              // 0..2047
      const int kk = idx >> 5, n4 = (idx & 31) * 4;
      const float4 v4 = *(const float4*)&psrc[(size_t)kk * NF + n4];
      const float fe[4] = {v4.x, v4.y, v4.z, v4.w};
#pragma unroll
      for (int e = 0; e < 4; ++e) {
        const int n = n4 + e;
        const int u = ((n >> 4) * 2 + (kk >> 5)) * 64 + (n & 15) + ((kk >> 3) & 3) * 16;
        Bs[u * 8 + (kk & 7)] = bfbits(fe[e]);
      }
    }
    __syncthreads();
    // ---- proj GEMM 64x128xK=64 + elu+1 ----
    f32x4 p[2][4] = {};
#pragma unroll
    for (int s = 0; s < 2; ++s) {
#pragma unroll
      for (int mb = 0; mb < 2; ++mb) {
        const bf16x8 af = *(const bf16x8*)&QK[((((size_t)(wr * 2 + mb)) * 2 + s) * 64 + lane) * 8];
#pragma unroll
        for (int nb = 0; nb < 4; ++nb) {
          const bf16x8 bv = *(const bf16x8*)&Bs[(((wc * 4 + nb) * 2 + s) * 64 + lane) * 8];
          p[mb][nb] = __builtin_amdgcn_mfma_f32_16x16x32_bf16(af, bv, p[mb][nb], 0, 0, 0);
        }
      }
    }
    unsigned short* dst = (src ? k_pk : q_pk) + (size_t)h * 262144;
#pragma unroll
    for (int mb = 0; mb < 2; ++mb) {
#pragma unroll
      for (int nb = 0; nb < 4; ++nb) {
        unsigned short vb[4];
#pragma unroll
        for (int r = 0; r < 4; ++r) {
          const float vv = p[mb][nb][r];
          vb[r] = f2bf(vv > 0.f ? vv + 1.f : expf(vv));
        }
        const size_t base = ((size_t)(c * 4 + wr * 2 + mb) * 4 + wc * 2 + (nb >> 1)) * 64 +
                            ((nb & 1) * 2 + (r16 >> 3)) * 16;
        const int elem = r16 & 7;
#pragma unroll
        for (int r = 0; r < 4; ++r)
          dst[(base + kg * 4 + r) * 8 + elem] = vb[r];
        if (src == 1) {
          const size_t u = (size_t)(h * 32 + c) * 1024 +
              ((size_t)(wc * 4 + nb) * 2 + wr) * 64 + r16 + (mb * 2 + (kg >> 1)) * 16;
          *(ushort4*)&kT_pk[u * 8 + (kg & 1) * 4] = *(ushort4*)&vb[0];
        }
      }
    }
  } else {
    // ---- V -> vT_pk PK(80,64) per (h,c), transposed ----
    const int h = bx - 16;
#pragma unroll
    for (int mb = 0; mb < 2; ++mb) {
#pragma unroll
      for (int nb = 0; nb < 2; ++nb) {
        const f32x4 a = mb == 0 ? (nb == 0 ? acc00 : acc01) : (nb == 0 ? acc10 : acc11);
        const int vc = wc * 32 + nb * 16 + r16;
        const size_t u = (size_t)(h * 32 + c) * 640 +
            ((size_t)(vc >> 4) * 2 + wr) * 64 + (vc & 15) + (mb * 2 + (kg >> 1)) * 16;
        ushort4 rr;
        rr.x = f2bf(a[0]); rr.y = f2bf(a[1]); rr.z = f2bf(a[2]); rr.w = f2bf(a[3]);
        *(ushort4*)&vT_pk[u * 8 + (kg & 1) * 4] = rr;
      }
    }
    // ones tile (V'' col 64 = 1.0, 65..79 = 0)
    if (t < 128) {
      const int kt = t >> 6, ln = t & 63;
      const unsigned short val = ((ln & 15) == 0) ? (unsigned short)0x3F80 : (unsigned short)0;
      unsigned short o8[8];
#pragma unroll
      for (int e = 0; e < 8; ++e) o8[e] = val;
      const size_t u = (size_t)(h * 32 + c) * 640 + (8 + kt) * 64 + ln;
      *(ushort4*)&vT_pk[u * 8]     = *(ushort4*)&o8[0];
      *(ushort4*)&vT_pk[u * 8 + 4] = *(ushort4*)&o8[4];
    }
  }
}

// ============ fused chunk-sums + exclusive scan (software-pipelined) ============
// grid (5 vtiles, NH), 4 waves; MFMA accumulator IS the running prefix.
// Chunk c+1's operands are prefetched during chunk c's MFMA chain.
__global__ __launch_bounds__(256) void sums_scan(
    const unsigned short* __restrict__ kT_pk, const unsigned short* __restrict__ vT_pk,
    unsigned short* __restrict__ kvpre_pk)
{
  const int lane = threadIdx.x & 63, w = threadIdx.x >> 6;
  const int vt = blockIdx.x, h = blockIdx.y;
  const int r16 = lane & 15, kg = lane >> 4;
  f32x4 acc0 = {0.f, 0.f, 0.f, 0.f}, acc1 = acc0;
  bf16x8 caf00, caf01, caf10, caf11, cbf0, cbf1;
  {
    const unsigned short* kb = kT_pk + (size_t)(h * 32) * 8192;
    const unsigned short* vb = vT_pk + (size_t)(h * 32) * 5120;
    cbf0  = *(const bf16x8*)(vb + ((size_t)(vt * 2 + 0) * 64 + lane) * 8);
    cbf1  = *(const bf16x8*)(vb + ((size_t)(vt * 2 + 1) * 64 + lane) * 8);
    caf00 = *(const bf16x8*)(kb + (((size_t)(w * 2 + 0) * 2 + 0) * 64 + lane) * 8);
    caf01 = *(const bf16x8*)(kb + (((size_t)(w * 2 + 0) * 2 + 1) * 64 + lane) * 8);
    caf10 = *(const bf16x8*)(kb + (((size_t)(w * 2 + 1) * 2 + 0) * 64 + lane) * 8);
    caf11 = *(const bf16x8*)(kb + (((size_t)(w * 2 + 1) * 2 + 1) * 64 + lane) * 8);
  }
  for (int c = 0; c < NCHUNK; ++c) {
    // store kvpre(c) = exclusive prefix (acc before adding chunk c)
    unsigned short* dst = kvpre_pk + (size_t)(h * 32 + c) * 1280 * 8;
    {
      unsigned short vb4[4];
#pragma unroll
      for (int r = 0; r < 4; ++r) vb4[r] = f2bf(acc0[r]);
      const size_t u0 = (size_t)(vt * 4 + w) * 64 + r16 + (0 * 2 + (kg >> 1)) * 16;
      *(ushort4*)&dst[u0 * 8 + (kg & 1) * 4] = *(ushort4*)&vb4[0];
#pragma unroll
      for (int r = 0; r < 4; ++r) vb4[r] = f2bf(acc1[r]);
      const size_t u1 = (size_t)(vt * 4 + w) * 64 + r16 + (1 * 2 + (kg >> 1)) * 16;
      *(ushort4*)&dst[u1 * 8 + (kg & 1) * 4] = *(ushort4*)&vb4[0];
    }
    // prefetch chunk c+1 while the MFMA chain below runs
    bf16x8 naf00 = caf00, naf01 = caf01, naf10 = caf10, naf11 = caf11;
    bf16x8 nbf0 = cbf0, nbf1 = cbf1;
    if (c < NCHUNK - 1) {
      const unsigned short* kb = kT_pk + (size_t)(h * 32 + c + 1) * 8192;
      const unsigned short* vb = vT_pk + (size_t)(h * 32 + c + 1) * 5120;
      nbf0  = *(const bf16x8*)(vb + ((size_t)(vt * 2 + 0) * 64 + lane) * 8);
      nbf1  = *(const bf16x8*)(vb + ((size_t)(vt * 2 + 1) * 64 + lane) * 8);
      naf00 = *(const bf16x8*)(kb + (((size_t)(w * 2 + 0) * 2 + 0) * 64 + lane) * 8);
      naf01 = *(const bf16x8*)(kb + (((size_t)(w * 2 + 0) * 2 + 1) * 64 + lane) * 8);
      naf10 = *(const bf16x8*)(kb + (((size_t)(w * 2 + 1) * 2 + 0) * 64 + lane) * 8);
      naf11 = *(const bf16x8*)(kb + (((size_t)(w * 2 + 1) * 2 + 1) * 64 + lane) * 8);
    }
    // same accumulation order as before: s=0 then s=1 per acc
    acc0 = __builtin_amdgcn_mfma_f32_16x16x32_bf16(caf00, cbf0, acc0, 0, 0, 0);
    acc0 = __builtin_amdgcn_mfma_f32_16x16x32_bf16(caf01, cbf1, acc0, 0, 0, 0);
    acc1 = __builtin_amdgcn_mfma_f32_16x16x32_bf16(caf10, cbf0, acc1, 0, 0, 0);
    acc1 = __builtin_amdgcn_mfma_f32_16x16x32_bf16(caf11, cbf1, acc1, 0, 0, 0);
    caf00 = naf00; caf01 = naf01; caf10 = naf10; caf11 = naf11;
    cbf0 = nbf0; cbf1 = nbf1;
  }
}

// ============ chunk attention (round-8 proven code) ============
__global__ __launch_bounds__(256) void chunk_attn(
    const unsigned short* __restrict__ q_pk, const unsigned short* __restrict__ k_pk,
    const unsigned short* __restrict__ kvpre_pk, const unsigned short* __restrict__ vT_pk,
    unsigned short* __restrict__ attn_pk)
{
  __shared__ unsigned short P[4096];   // PK(64,64), 8 KB
  __shared__ float den[64];
  const int lane = threadIdx.x & 63, w = threadIdx.x >> 6;
  const int wr = w >> 1, wc = w & 1;
  const int c = blockIdx.x, h = blockIdx.y;
  const int r16 = lane & 15, kg = lane >> 4;
  const unsigned short* qb = q_pk + (size_t)h * 262144;
  const unsigned short* kb = k_pk + (size_t)h * 262144;
  bf16x8 qa[2][4];
#pragma unroll
  for (int amb = 0; amb < 2; ++amb)
#pragma unroll
    for (int ks = 0; ks < 4; ++ks)
      qa[amb][ks] = *(const bf16x8*)(qb +
          (((size_t)(c * 4 + wr * 2 + amb) * 4 + ks) * 64 + lane) * 8);
  {
    f32x4 accS[2][2] = {};
#pragma unroll
    for (int ks = 0; ks < 4; ++ks) {
#pragma unroll
      for (int bnb = 0; bnb < 2; ++bnb) {
        const bf16x8 bf = *(const bf16x8*)(kb +
            (((size_t)(c * 4 + wc * 2 + bnb) * 4 + ks) * 64 + lane) * 8);
#pragma unroll
        for (int amb = 0; amb < 2; ++amb)
          accS[amb][bnb] = __builtin_amdgcn_mfma_f32_16x16x32_bf16(qa[amb][ks], bf, accS[amb][bnb], 0, 0, 0);
      }
    }
#pragma unroll
    for (int amb = 0; amb < 2; ++amb)
#pragma unroll
      for (int bnb = 0; bnb < 2; ++bnb) {
        const int ck = wc * 32 + bnb * 16 + r16;
        const size_t u = ((size_t)(wr * 2 + amb) * 2 + wc) * 64 + (bnb * 2 + (r16 >> 3)) * 16;
        const int elem = r16 & 7;
#pragma unroll
        for (int r = 0; r < 4; ++r) {
          const int rq = wr * 32 + amb * 16 + kg * 4 + r;
          P[(u + kg * 4 + r) * 8 + elem] = (ck <= rq) ? f2bf(accS[amb][bnb][r]) : (unsigned short)0;
        }
      }
  }
  __syncthreads();
  const int nnt = wc ? 2 : 3;
  const int ntb = wc ? 3 : 0;
  const unsigned short* kvp = kvpre_pk + (size_t)(h * 32 + c) * 1280 * 8;
  const unsigned short* vtb = vT_pk + (size_t)(h * 32 + c) * 640 * 8;
  f32x4 acc[2][3] = {};
#pragma unroll
  for (int ks = 0; ks < 4; ++ks) {
    bf16x8 bfr[3];
    for (int jj = 0; jj < 3; ++jj)
      if (jj < nnt)
        bfr[jj] = *(const bf16x8*)(kvp + (((size_t)(ntb + jj) * 4 + ks) * 64 + lane) * 8);
#pragma unroll
    for (int amb = 0; amb < 2; ++amb)
      for (int jj = 0; jj < 3; ++jj)
        if (jj < nnt)
          acc[amb][jj] = __builtin_amdgcn_mfma_f32_16x16x32_bf16(qa[amb][ks], bfr[jj], acc[amb][jj], 0, 0, 0);
  }
#pragma unroll
  for (int ks = 0; ks < 2; ++ks) {
    bf16x8 bfr[3];
    for (int jj = 0; jj < 3; ++jj)
      if (jj < nnt)
        bfr[jj] = *(const bf16x8*)(vtb + (((size_t)(ntb + jj) * 2 + ks) * 64 + lane) * 8);
#pragma unroll
    for (int amb = 0; amb < 2; ++amb) {
      const bf16x8 pf = *(const bf16x8*)&P[((((size_t)(wr * 2 + amb)) * 2 + ks) * 64 + lane) * 8];
      for (int jj = 0; jj < 3; ++jj)
        if (jj < nnt)
          acc[amb][jj] = __builtin_amdgcn_mfma_f32_16x16x32_bf16(pf, bfr[jj], acc[amb][jj], 0, 0, 0);
    }
  }
  if (wc == 1 && r16 == 0) {
#pragma unroll
    for (int amb = 0; amb < 2; ++amb)
#pragma unroll
      for (int r = 0; r < 4; ++r)
        den[wr * 32 + amb * 16 + kg * 4 + r] = acc[amb][1][r] + EPS_C;
  }
  __syncthreads();
#pragma unroll
  for (int amb = 0; amb < 2; ++amb) {
    for (int jj = 0; jj < 3; ++jj) {
      const int nt = ntb + jj;
      if (nt >= 4 || jj >= nnt) continue;
      const int acol = h * 64 + nt * 16 + r16;
      const size_t base = ((size_t)(c * 4 + wr * 2 + amb) * 16 + (acol >> 5)) * 64 +
                          ((nt * 2 + (r16 >> 3)) & 3) * 16;
      const int elem = acol & 7;
#pragma unroll
      for (int r = 0; r < 4; ++r) {
        const float dinv = 1.0f / den[wr * 32 + amb * 16 + kg * 4 + r];
        attn_pk[(base + kg * 4 + r) * 8 + elem] = f2bf(acc[amb][jj][r] * dinv);
      }
    }
  }
}

// ============ out = attn @ W_out + b_out (W_out fp32, staged in LDS) ============
// grid (8, 32). A from packed attn; B staged per-128-K-slice like qkv_proj.
__global__ __launch_bounds__(256) void gemm_out(
    const unsigned short* __restrict__ Apk, const float* __restrict__ W_out,
    const float* __restrict__ bias, float* __restrict__ Cf)
{
  __shared__ unsigned short Bs[8192];   // PK(64,128) slice, 16 KB
  const int t = threadIdx.x;
  const int lane = t & 63, w = t >> 6;
  const int wr = w >> 1, wc = w & 1;
  const int m0 = blockIdx.y * 64 + wr * 32;
  const int n0b = blockIdx.x * 64;
  const int n0 = n0b + wc * 32;
  const int r16 = lane & 15, kg = lane >> 4;
  const unsigned short* a0 = Apk + ((size_t)(m0 >> 4) * 16 * 64 + lane) * 8;
  const unsigned short* a1 = a0 + (size_t)16 * 512;
  f32x4 acc00 = {0.f, 0.f, 0.f, 0.f}, acc01 = acc00, acc10 = acc00, acc11 = acc00;
  for (int st = 0; st < 4; ++st) {
    const float* wsrc = W_out + (size_t)(st * 128) * DMODEL + n0b;
#pragma unroll
    for (int i = 0; i < 8; ++i) {
      const int idx = t * 8 + i;              // 0..2047
      const int kl = idx >> 4, n4 = (idx & 15) * 4;
      const float4 v4 = *(const float4*)&wsrc[(size_t)kl * DMODEL + n4];
      const float fe[4] = {v4.x, v4.y, v4.z, v4.w};
#pragma unroll
      for (int e = 0; e < 4; ++e) {
        const int n = n4 + e;
        const int u = ((n >> 4) * 4 + (kl >> 5)) * 64 + (n & 15) + ((kl >> 3) & 3) * 16;
        Bs[u * 8 + (kl & 7)] = bfbits(fe[e]);
      }
    }
    __syncthreads();
#pragma unroll
    for (int sl = 0; sl < 4; ++sl) {
      const int s = st * 4 + sl;
      const bf16x8 af0 = *(const bf16x8*)(a0 + (size_t)s * 512);
      const bf16x8 af1 = *(const bf16x8*)(a1 + (size_t)s * 512);
      const bf16x8 bv0 = *(const bf16x8*)&Bs[(((wc * 2 + 0) * 4 + sl) * 64 + lane) * 8];
      const bf16x8 bv1 = *(const bf16x8*)&Bs[(((wc * 2 + 1) * 4 + sl) * 64 + lane) * 8];
      acc00 = __builtin_amdgcn_mfma_f32_16x16x32_bf16(af0, bv0, acc00, 0, 0, 0);
      acc01 = __builtin_amdgcn_mfma_f32_16x16x32_bf16(af0, bv1, acc01, 0, 0, 0);
      acc10 = __builtin_amdgcn_mfma_f32_16x16x32_bf16(af1, bv0, acc10, 0, 0, 0);
      acc11 = __builtin_amdgcn_mfma_f32_16x16x32_bf16(af1, bv1, acc11, 0, 0, 0);
    }
    __syncthreads();
  }
#pragma unroll
  for (int mb = 0; mb < 2; ++mb) {
#pragma unroll
    for (int nb = 0; nb < 2; ++nb) {
      const f32x4 a = mb == 0 ? (nb == 0 ? acc00 : acc01) : (nb == 0 ? acc10 : acc11);
      const int col = n0 + nb * 16 + r16;
      const float bv = bias[col];
#pragma unroll
      for (int r = 0; r < 4; ++r)
        Cf[(size_t)(m0 + mb * 16 + kg * 4 + r) * DMODEL + col] = a[r] + bv;
    }
  }
}

extern "C" void kernel_launch(void* const* d_in, const int* in_sizes, int n_in,
                              void* d_out, int out_size, void* d_ws, size_t ws_size,
                              hipStream_t stream) {
  const float* x     = (const float*)d_in[0];
  const float* proj  = (const float*)d_in[1];
  const float* W_qkv = (const float*)d_in[2];
  const float* W_out = (const float*)d_in[3];
  const float* b_out = (const float*)d_in[4];
  float* out = (float*)d_out;

  unsigned short* q_pk     = (unsigned short*)d_ws;          // 2,097,152 us
  unsigned short* k_pk     = q_pk + 2097152;                 // 2,097,152
  unsigned short* kT_pk    = k_pk + 2097152;                 // 2,097,152
  unsigned short* vT_pk    = kT_pk + 2097152;                // 1,310,720
  unsigned short* kvpre_pk = vT_pk + 1310720;                // 2,621,440
  unsigned short* attn_pk  = kvpre_pk + 2621440;             // 1,048,576
  // total 11,272,192 ushorts ~ 22.5 MB

  // 1) fused qkv GEMM (fp32-in) + proj + elu -> q_pk, k_pk, kT_pk, vT_pk
  qkv_proj<<<dim3(24, NCHUNK), 256, 0, stream>>>(
      x, W_qkv, proj, q_pk, k_pk, kT_pk, vT_pk);
  // 2) fused chunk-sums + exclusive prefix (pipelined) -> kvpre_pk
  sums_scan<<<dim3(5, NH), 256, 0, stream>>>(kT_pk, vT_pk, kvpre_pk);
  // 3) chunk attention -> attn_pk
  chunk_attn<<<dim3(NCHUNK, NH), 256, 0, stream>>>(
      q_pk, k_pk, kvpre_pk, vT_pk, attn_pk);
  // 4) out = attn @ W_out + b_out (fp32-in)
  gemm_out<<<dim3(DMODEL / 64, NTOK / 64), 256, 0, stream>>>(
      attn_pk, W_out, b_out, out);
}

// Round 12
// 52.670 us; speedup vs baseline: 1.5611x; 1.5611x over previous
//
#include <hip/hip_runtime.h>
#include <math.h>

#define NTOK 2048
#define DMODEL 512
#define NH 8
#define HD 64
#define NF 128
#define QKV_LD 1536
#define CHUNK 64
#define NCHUNK 32
#define EPS_C 1e-8f

typedef __bf16 bf16x8 __attribute__((ext_vector_type(8)));
typedef float f32x4 __attribute__((ext_vector_type(4)));

__device__ inline unsigned short f2bf(float f) {
  union { float f; unsigned u; } v; v.f = f;
  unsigned r = v.u + 0x7FFF + ((v.u >> 16) & 1);   // RNE
  return (unsigned short)(r >> 16);
}

// Packed fragment layout PK(M,K) for MFMA operand (A: [m][k]; B: [n][k]):
//   unit(m,k)  = ((m>>4)*(K>>5) + (k>>5))*64 + (m&15) + ((k>>3)&3)*16
//   ushort idx = unit*8 + (k&7)

// ============ pack_all ============
// jobs 0-3: inputs -> packed bf16. job 4: vT_pk n-tile 4 (col 64 = ones).
__global__ __launch_bounds__(256) void pack_all(
    const float* __restrict__ x, const float* __restrict__ W_qkv,
    const float* __restrict__ W_out, const float* __restrict__ proj,
    unsigned short* __restrict__ xpk, unsigned short* __restrict__ wqkvpk,
    unsigned short* __restrict__ woutpk, unsigned short* __restrict__ projpk,
    unsigned short* __restrict__ vT_pk)
{
  const int tid = blockIdx.x * 256 + threadIdx.x;
  const int job = blockIdx.y;
  unsigned short o[8];
  if (job == 0) {
    if (tid >= 131072) return;
    const int lane = tid & 63, blk = tid >> 6;
    const int bk = blk & 15, bm = blk >> 4;
    const int m = bm * 16 + (lane & 15), k = bk * 32 + (lane >> 4) * 8;
    const float4 v0 = *(const float4*)&x[(size_t)m * 512 + k];
    const float4 v1 = *(const float4*)&x[(size_t)m * 512 + k + 4];
    o[0] = f2bf(v0.x); o[1] = f2bf(v0.y); o[2] = f2bf(v0.z); o[3] = f2bf(v0.w);
    o[4] = f2bf(v1.x); o[5] = f2bf(v1.y); o[6] = f2bf(v1.z); o[7] = f2bf(v1.w);
    *(ushort4*)&xpk[(size_t)tid * 8]     = *(ushort4*)&o[0];
    *(ushort4*)&xpk[(size_t)tid * 8 + 4] = *(ushort4*)&o[4];
  } else if (job == 1) {
    if (tid >= 98304) return;
    const int lane = tid & 63, blk = tid >> 6;
    const int bk = blk & 15, bn = blk >> 4;
    const int n = bn * 16 + (lane & 15), k = bk * 32 + (lane >> 4) * 8;
#pragma unroll
    for (int e = 0; e < 8; ++e) o[e] = f2bf(W_qkv[(size_t)(k + e) * QKV_LD + n]);
    *(ushort4*)&wqkvpk[(size_t)tid * 8]     = *(ushort4*)&o[0];
    *(ushort4*)&wqkvpk[(size_t)tid * 8 + 4] = *(ushort4*)&o[4];
  } else if (job == 2) {
    if (tid >= 32768) return;
    const int lane = tid & 63, blk = tid >> 6;
    const int bk = blk & 15, bn = blk >> 4;
    const int n = bn * 16 + (lane & 15), k = bk * 32 + (lane >> 4) * 8;
#pragma unroll
    for (int e = 0; e < 8; ++e) o[e] = f2bf(W_out[(size_t)(k + e) * DMODEL + n]);
    *(ushort4*)&woutpk[(size_t)tid * 8]     = *(ushort4*)&o[0];
    *(ushort4*)&woutpk[(size_t)tid * 8 + 4] = *(ushort4*)&o[4];
  } else if (job == 3) {
    if (tid >= 8192) return;
    const int lane = tid & 63, blk = (tid >> 6) & 15, h = tid >> 10;
    const int bk = blk & 1, bn = blk >> 1;
    const int n = bn * 16 + (lane & 15), k = bk * 32 + (lane >> 4) * 8;
#pragma unroll
    for (int e = 0; e < 8; ++e) o[e] = f2bf(proj[(size_t)h * HD * NF + (size_t)(k + e) * NF + n]);
    *(ushort4*)&projpk[(size_t)tid * 8]     = *(ushort4*)&o[0];
    *(ushort4*)&projpk[(size_t)tid * 8 + 4] = *(ushort4*)&o[4];
  } else {
    if (tid >= 32768) return;                       // 256 (h,c) x 2 kt x 64 lanes
    const int hc = tid >> 7, kt = (tid >> 6) & 1, lane = tid & 63;
    const unsigned short val = ((lane & 15) == 0) ? (unsigned short)0x3F80 : (unsigned short)0;
    const size_t u = (size_t)hc * 640 + (4 * 2 + kt) * 64 + lane;
#pragma unroll
    for (int e = 0; e < 8; ++e) o[e] = val;
    *(ushort4*)&vT_pk[u * 8]     = *(ushort4*)&o[0];
    *(ushort4*)&vT_pk[u * 8 + 4] = *(ushort4*)&o[4];
  }
}

// ============ fused qkv GEMM + proj + elu+1 ============
// grid (24, 32): blockIdx.x = 64-col tile of qkv (0-7 Q, 8-15 K, 16-23 V),
// blockIdx.y = chunk (64 tokens). Q/K blocks: main GEMM -> LDS (packed) ->
// proj MFMA -> elu+1 -> q_pk/k_pk (+ kT_pk for K). V blocks -> vT_pk.
__global__ __launch_bounds__(256) void qkv_proj(
    const unsigned short* __restrict__ Apk, const unsigned short* __restrict__ Bpk,
    const unsigned short* __restrict__ projpk,
    unsigned short* __restrict__ q_pk, unsigned short* __restrict__ k_pk,
    unsigned short* __restrict__ kT_pk, unsigned short* __restrict__ vT_pk)
{
  __shared__ unsigned short QK[4096];   // PK(64,64), 8 KB
  const int lane = threadIdx.x & 63, w = threadIdx.x >> 6;
  const int wr = w >> 1, wc = w & 1;
  const int c = blockIdx.y;
  const int m0 = c * 64 + wr * 32;
  const int n0 = blockIdx.x * 64 + wc * 32;
  const unsigned short* a0 = Apk + ((size_t)(m0 >> 4) * 16 * 64 + lane) * 8;
  const unsigned short* a1 = a0 + (size_t)16 * 512;
  const unsigned short* b0 = Bpk + ((size_t)(n0 >> 4) * 16 * 64 + lane) * 8;
  const unsigned short* b1 = b0 + (size_t)16 * 512;
  f32x4 acc00 = {0.f, 0.f, 0.f, 0.f}, acc01 = acc00, acc10 = acc00, acc11 = acc00;
#pragma unroll 4
  for (int s = 0; s < 16; ++s) {
    const bf16x8 af0 = *(const bf16x8*)(a0 + (size_t)s * 512);
    const bf16x8 af1 = *(const bf16x8*)(a1 + (size_t)s * 512);
    const bf16x8 bv0 = *(const bf16x8*)(b0 + (size_t)s * 512);
    const bf16x8 bv1 = *(const bf16x8*)(b1 + (size_t)s * 512);
    acc00 = __builtin_amdgcn_mfma_f32_16x16x32_bf16(af0, bv0, acc00, 0, 0, 0);
    acc01 = __builtin_amdgcn_mfma_f32_16x16x32_bf16(af0, bv1, acc01, 0, 0, 0);
    acc10 = __builtin_amdgcn_mfma_f32_16x16x32_bf16(af1, bv0, acc10, 0, 0, 0);
    acc11 = __builtin_amdgcn_mfma_f32_16x16x32_bf16(af1, bv1, acc11, 0, 0, 0);
  }
  const int r16 = lane & 15, kg = lane >> 4;
  if (blockIdx.x < 16) {
    const int src = blockIdx.x >> 3, h = blockIdx.x & 7;
    // ---- qkv tile -> LDS PK(64,64) ----
#pragma unroll
    for (int mb = 0; mb < 2; ++mb) {
#pragma unroll
      for (int nb = 0; nb < 2; ++nb) {
        const f32x4 a = mb == 0 ? (nb == 0 ? acc00 : acc01) : (nb == 0 ? acc10 : acc11);
        const size_t u = ((size_t)(wr * 2 + mb) * 2 + wc) * 64 +
                         (nb * 2 + (r16 >> 3)) * 16 + kg * 4;
        const int elem = r16 & 7;
#pragma unroll
        for (int r = 0; r < 4; ++r)
          QK[(u + r) * 8 + elem] = f2bf(a[r]);
      }
    }
    __syncthreads();
    // ---- proj GEMM: 64 tokens x 128 features x K=64, + elu+1 ----
    const unsigned short* bbase = projpk + (size_t)h * 8192 + (size_t)lane * 8;
    f32x4 p[2][4] = {};
#pragma unroll
    for (int s = 0; s < 2; ++s) {
#pragma unroll
      for (int mb = 0; mb < 2; ++mb) {
        const bf16x8 af = *(const bf16x8*)&QK[((((size_t)(wr * 2 + mb)) * 2 + s) * 64 + lane) * 8];
#pragma unroll
        for (int nb = 0; nb < 4; ++nb) {
          const bf16x8 bv = *(const bf16x8*)(bbase + (size_t)((wc * 4 + nb) * 2 + s) * 512);
          p[mb][nb] = __builtin_amdgcn_mfma_f32_16x16x32_bf16(af, bv, p[mb][nb], 0, 0, 0);
        }
      }
    }
    unsigned short* dst = (src ? k_pk : q_pk) + (size_t)h * 262144;
#pragma unroll
    for (int mb = 0; mb < 2; ++mb) {
#pragma unroll
      for (int nb = 0; nb < 4; ++nb) {
        unsigned short vb[4];
#pragma unroll
        for (int r = 0; r < 4; ++r) {
          const float v = p[mb][nb][r];
          vb[r] = f2bf(v > 0.f ? v + 1.f : expf(v));
        }
        const size_t base = ((size_t)(c * 4 + wr * 2 + mb) * 4 + wc * 2 + (nb >> 1)) * 64 +
                            ((nb & 1) * 2 + (r16 >> 3)) * 16;
        const int elem = r16 & 7;
#pragma unroll
        for (int r = 0; r < 4; ++r)
          dst[(base + kg * 4 + r) * 8 + elem] = vb[r];
        if (src == 1) {
          // transposed copy for the sums GEMM: kT PK(128,64) per (h,c)
          const size_t u = (size_t)(h * 32 + c) * 1024 +
              ((size_t)(wc * 4 + nb) * 2 + wr) * 64 + r16 + (mb * 2 + (kg >> 1)) * 16;
          *(ushort4*)&kT_pk[u * 8 + (kg & 1) * 4] = *(ushort4*)&vb[0];
        }
      }
    }
  } else {
    // ---- V -> vT_pk PK(80,64) per (h,c), transposed ----
    const int h = blockIdx.x - 16;
#pragma unroll
    for (int mb = 0; mb < 2; ++mb) {
#pragma unroll
      for (int nb = 0; nb < 2; ++nb) {
        const f32x4 a = mb == 0 ? (nb == 0 ? acc00 : acc01) : (nb == 0 ? acc10 : acc11);
        const int vc = wc * 32 + nb * 16 + r16;
        const size_t u = (size_t)(h * 32 + c) * 640 +
            ((size_t)(vc >> 4) * 2 + wr) * 64 + (vc & 15) + (mb * 2 + (kg >> 1)) * 16;
        ushort4 rr;
        rr.x = f2bf(a[0]); rr.y = f2bf(a[1]); rr.z = f2bf(a[2]); rr.w = f2bf(a[3]);
        *(ushort4*)&vT_pk[u * 8 + (kg & 1) * 4] = rr;
      }
    }
  }
}

// ============ fused chunk-sums + exclusive scan ============
// grid (5 vtiles, NH), 4 waves; wave w owns features w*32..+31, block owns
// V''-cols vt*16..+15. The MFMA accumulator IS the running prefix:
// for c: emit acc (= sum of chunks < c) -> kvpre_pk[c]; acc += kT(c)@V''(c).
__global__ __launch_bounds__(256) void sums_scan(
    const unsigned short* __restrict__ kT_pk, const unsigned short* __restrict__ vT_pk,
    unsigned short* __restrict__ kvpre_pk)
{
  const int lane = threadIdx.x & 63, w = threadIdx.x >> 6;
  const int vt = blockIdx.x, h = blockIdx.y;
  const int r16 = lane & 15, kg = lane >> 4;
  f32x4 acc[2] = {};
  for (int c = 0; c < NCHUNK; ++c) {
    unsigned short* dst = kvpre_pk + (size_t)(h * 32 + c) * 1280 * 8;
#pragma unroll
    for (int mb = 0; mb < 2; ++mb) {
      unsigned short vb[4];
#pragma unroll
      for (int r = 0; r < 4; ++r) vb[r] = f2bf(acc[mb][r]);
      const size_t u = (size_t)(vt * 4 + w) * 64 + r16 + (mb * 2 + (kg >> 1)) * 16;
      *(ushort4*)&dst[u * 8 + (kg & 1) * 4] = *(ushort4*)&vb[0];
    }
    const unsigned short* kb = kT_pk + (size_t)(h * 32 + c) * 1024 * 8;
    const unsigned short* vb_ = vT_pk + (size_t)(h * 32 + c) * 640 * 8;
#pragma unroll
    for (int s = 0; s < 2; ++s) {
      const bf16x8 bf = *(const bf16x8*)(vb_ + (((size_t)vt * 2 + s) * 64 + lane) * 8);
#pragma unroll
      for (int mb = 0; mb < 2; ++mb) {
        const bf16x8 af = *(const bf16x8*)(kb + ((((size_t)(w * 2 + mb)) * 2 + s) * 64 + lane) * 8);
        acc[mb] = __builtin_amdgcn_mfma_f32_16x16x32_bf16(af, bf, acc[mb], 0, 0, 0);
      }
    }
  }
}

// ============ packed bf16 MFMA GEMM (final projection) ============
__global__ __launch_bounds__(256) void gemm_out(
    const unsigned short* __restrict__ Apk, const unsigned short* __restrict__ Bpk,
    const float* __restrict__ bias, float* __restrict__ Cf, int K, int ldc)
{
  const int lane = threadIdx.x & 63, w = threadIdx.x >> 6;
  const int wr = w >> 1, wc = w & 1;
  const int m0 = blockIdx.y * 64 + wr * 32;
  const int n0 = blockIdx.x * 64 + wc * 32;
  const int ks = K >> 5;
  const unsigned short* a0 = Apk + ((size_t)(m0 >> 4) * ks * 64 + lane) * 8;
  const unsigned short* a1 = a0 + (size_t)ks * 512;
  const unsigned short* b0 = Bpk + ((size_t)(n0 >> 4) * ks * 64 + lane) * 8;
  const unsigned short* b1 = b0 + (size_t)ks * 512;
  f32x4 acc00 = {0.f, 0.f, 0.f, 0.f}, acc01 = acc00, acc10 = acc00, acc11 = acc00;
#pragma unroll 4
  for (int s = 0; s < ks; ++s) {
    const bf16x8 af0 = *(const bf16x8*)(a0 + (size_t)s * 512);
    const bf16x8 af1 = *(const bf16x8*)(a1 + (size_t)s * 512);
    const bf16x8 bv0 = *(const bf16x8*)(b0 + (size_t)s * 512);
    const bf16x8 bv1 = *(const bf16x8*)(b1 + (size_t)s * 512);
    acc00 = __builtin_amdgcn_mfma_f32_16x16x32_bf16(af0, bv0, acc00, 0, 0, 0);
    acc01 = __builtin_amdgcn_mfma_f32_16x16x32_bf16(af0, bv1, acc01, 0, 0, 0);
    acc10 = __builtin_amdgcn_mfma_f32_16x16x32_bf16(af1, bv0, acc10, 0, 0, 0);
    acc11 = __builtin_amdgcn_mfma_f32_16x16x32_bf16(af1, bv1, acc11, 0, 0, 0);
  }
  const int r16 = lane & 15, kg = lane >> 4;
#pragma unroll
  for (int mb = 0; mb < 2; ++mb) {
#pragma unroll
    for (int nb = 0; nb < 2; ++nb) {
      const f32x4 a = mb == 0 ? (nb == 0 ? acc00 : acc01) : (nb == 0 ? acc10 : acc11);
      const int col = n0 + nb * 16 + r16;
      const float bv = bias[col];
#pragma unroll
      for (int r = 0; r < 4; ++r)
        Cf[(size_t)(m0 + mb * 16 + kg * 4 + r) * ldc + col] = a[r] + bv;
    }
  }
}

// ============ chunk attention: S=QK^T -> mask -> P; O = Q@KVpre'' + P@V'' ============
// col 64 of the combined accumulator IS the denominator. grid (NCHUNK, NH), 4 waves.
__global__ __launch_bounds__(256) void chunk_attn(
    const unsigned short* __restrict__ q_pk, const unsigned short* __restrict__ k_pk,
    const unsigned short* __restrict__ kvpre_pk, const unsigned short* __restrict__ vT_pk,
    unsigned short* __restrict__ attn_pk)
{
  __shared__ unsigned short P[4096];   // PK(64,64) = 512 units, 8 KB
  __shared__ float den[64];
  const int lane = threadIdx.x & 63, w = threadIdx.x >> 6;
  const int wr = w >> 1, wc = w & 1;
  const int c = blockIdx.x, h = blockIdx.y;
  const int r16 = lane & 15, kg = lane >> 4;
  const unsigned short* qb = q_pk + (size_t)h * 262144;
  const unsigned short* kb = k_pk + (size_t)h * 262144;
  bf16x8 qa[2][4];
#pragma unroll
  for (int amb = 0; amb < 2; ++amb)
#pragma unroll
    for (int ks = 0; ks < 4; ++ks)
      qa[amb][ks] = *(const bf16x8*)(qb +
          (((size_t)(c * 4 + wr * 2 + amb) * 4 + ks) * 64 + lane) * 8);
  // ---- Phase A: S = Q K^T, causal mask, P -> LDS ----
  {
    f32x4 accS[2][2] = {};
#pragma unroll
    for (int ks = 0; ks < 4; ++ks) {
#pragma unroll
      for (int bnb = 0; bnb < 2; ++bnb) {
        const bf16x8 bf = *(const bf16x8*)(kb +
            (((size_t)(c * 4 + wc * 2 + bnb) * 4 + ks) * 64 + lane) * 8);
#pragma unroll
        for (int amb = 0; amb < 2; ++amb)
          accS[amb][bnb] = __builtin_amdgcn_mfma_f32_16x16x32_bf16(qa[amb][ks], bf, accS[amb][bnb], 0, 0, 0);
      }
    }
#pragma unroll
    for (int amb = 0; amb < 2; ++amb)
#pragma unroll
      for (int bnb = 0; bnb < 2; ++bnb) {
        const int ck = wc * 32 + bnb * 16 + r16;
        const size_t u = ((size_t)(wr * 2 + amb) * 2 + wc) * 64 + (bnb * 2 + (r16 >> 3)) * 16;
        const int elem = r16 & 7;
#pragma unroll
        for (int r = 0; r < 4; ++r) {
          const int rq = wr * 32 + amb * 16 + kg * 4 + r;
          P[(u + kg * 4 + r) * 8 + elem] = (ck <= rq) ? f2bf(accS[amb][bnb][r]) : (unsigned short)0;
        }
      }
  }
  __syncthreads();
  // ---- Phase B: O = Q @ KVpre'' + P @ V'' ----
  const int nnt = wc ? 2 : 3;
  const int ntb = wc ? 3 : 0;
  const unsigned short* kvp = kvpre_pk + (size_t)(h * 32 + c) * 1280 * 8;
  const unsigned short* vtb = vT_pk + (size_t)(h * 32 + c) * 640 * 8;
  f32x4 acc[2][3] = {};
#pragma unroll
  for (int ks = 0; ks < 4; ++ks) {
    bf16x8 bfr[3];
    for (int j = 0; j < 3; ++j)
      if (j < nnt)
        bfr[j] = *(const bf16x8*)(kvp + (((size_t)(ntb + j) * 4 + ks) * 64 + lane) * 8);
#pragma unroll
    for (int amb = 0; amb < 2; ++amb)
      for (int j = 0; j < 3; ++j)
        if (j < nnt)
          acc[amb][j] = __builtin_amdgcn_mfma_f32_16x16x32_bf16(qa[amb][ks], bfr[j], acc[amb][j], 0, 0, 0);
  }
#pragma unroll
  for (int ks = 0; ks < 2; ++ks) {
    bf16x8 bfr[3];
    for (int j = 0; j < 3; ++j)
      if (j < nnt)
        bfr[j] = *(const bf16x8*)(vtb + (((size_t)(ntb + j) * 2 + ks) * 64 + lane) * 8);
#pragma unroll
    for (int amb = 0; amb < 2; ++amb) {
      const bf16x8 pf = *(const bf16x8*)&P[((((size_t)(wr * 2 + amb)) * 2 + ks) * 64 + lane) * 8];
      for (int j = 0; j < 3; ++j)
        if (j < nnt)
          acc[amb][j] = __builtin_amdgcn_mfma_f32_16x16x32_bf16(pf, bfr[j], acc[amb][j], 0, 0, 0);
    }
  }
  if (wc == 1 && r16 == 0) {
#pragma unroll
    for (int amb = 0; amb < 2; ++amb)
#pragma unroll
      for (int r = 0; r < 4; ++r)
        den[wr * 32 + amb * 16 + kg * 4 + r] = acc[amb][1][r] + EPS_C;
  }
  __syncthreads();
#pragma unroll
  for (int amb = 0; amb < 2; ++amb) {
    for (int j = 0; j < 3; ++j) {
      const int nt = ntb + j;
      if (nt >= 4 || j >= nnt) continue;
      const int acol = h * 64 + nt * 16 + r16;
      const size_t base = ((size_t)(c * 4 + wr * 2 + amb) * 16 + (acol >> 5)) * 64 +
                          ((nt * 2 + (r16 >> 3)) & 3) * 16;
      const int elem = acol & 7;
#pragma unroll
      for (int r = 0; r < 4; ++r) {
        const float dinv = 1.0f / den[wr * 32 + amb * 16 + kg * 4 + r];
        attn_pk[(base + kg * 4 + r) * 8 + elem] = f2bf(acc[amb][j][r] * dinv);
      }
    }
  }
}

extern "C" void kernel_launch(void* const* d_in, const int* in_sizes, int n_in,
                              void* d_out, int out_size, void* d_ws, size_t ws_size,
                              hipStream_t stream) {
  const float* x     = (const float*)d_in[0];
  const float* proj  = (const float*)d_in[1];
  const float* W_qkv = (const float*)d_in[2];
  const float* W_out = (const float*)d_in[3];
  const float* b_out = (const float*)d_in[4];
  float* out = (float*)d_out;

  unsigned short* xpk      = (unsigned short*)d_ws;          // 1,048,576 us
  unsigned short* wqkvpk   = xpk + 1048576;                  //   786,432
  unsigned short* woutpk   = wqkvpk + 786432;                //   262,144
  unsigned short* projpk   = woutpk + 262144;                //    65,536
  unsigned short* q_pk     = projpk + 65536;                 // 2,097,152
  unsigned short* k_pk     = q_pk + 2097152;                 // 2,097,152
  unsigned short* kT_pk    = k_pk + 2097152;                 // 2,097,152
  unsigned short* vT_pk    = kT_pk + 2097152;                // 1,310,720
  unsigned short* kvpre_pk = vT_pk + 1310720;                // 2,621,440
  unsigned short* attn_pk  = kvpre_pk + 2621440;             // 1,048,576
  // total 13,434,880 ushorts ~ 26.9 MB

  // 0) pack inputs + constant V'' ones-tile
  pack_all<<<dim3(512, 5), 256, 0, stream>>>(x, W_qkv, W_out, proj,
                                             xpk, wqkvpk, woutpk, projpk, vT_pk);
  // 1) fused qkv GEMM + proj + elu -> q_pk, k_pk, kT_pk, vT_pk
  qkv_proj<<<dim3(QKV_LD / 64, NTOK / 64), 256, 0, stream>>>(
      xpk, wqkvpk, projpk, q_pk, k_pk, kT_pk, vT_pk);
  // 2) fused chunk-sums + exclusive prefix -> kvpre_pk (col 64 = kpre)
  sums_scan<<<dim3(5, NH), 256, 0, stream>>>(kT_pk, vT_pk, kvpre_pk);
  // 3) chunk attention -> attn_pk
  chunk_attn<<<dim3(NCHUNK, NH), 256, 0, stream>>>(
      q_pk, k_pk, kvpre_pk, vT_pk, attn_pk);
  // 4) out = attn @ W_out + b_out
  gemm_out<<<dim3(DMODEL / 64, NTOK / 64), 256, 0, stream>>>(
      attn_pk, woutpk, b_out, out, DMODEL, DMODEL);
}